// Round 3
// baseline (548.149 us; speedup 1.0000x reference)
//
#include <hip/hip_runtime.h>

#define N_TOK 4096
#define DIM   1024
#define NE    16
#define NF    512
#define TOPK  4
#define CAP   4096
#define NPAIR (N_TOK * TOPK)
#define MAXTILES 144   // sum ceil(cnt/128) <= 128 + 16

typedef _Float16 v8h __attribute__((ext_vector_type(8)));
typedef float    v4f __attribute__((ext_vector_type(4)));

// direct global->LDS DMA, 16B/lane, wave-uniform LDS base (CK-style casts)
__device__ __forceinline__ void async_load16(const void* g, void* l) {
    __builtin_amdgcn_global_load_lds(
        reinterpret_cast<const __attribute__((address_space(1))) unsigned int*>(
            reinterpret_cast<uintptr_t>(g)),
        reinterpret_cast<__attribute__((address_space(3))) unsigned int*>(
            reinterpret_cast<uintptr_t>(l)),
        16, 0, 0);
}

// ---------------------------------------------------------------- router ----
__global__ __launch_bounds__(64) void router_kernel(
    const float* __restrict__ x, const float* __restrict__ Wr,
    int* __restrict__ tokIdx, float* __restrict__ tokW)
{
    int t = blockIdx.x;
    int l = threadIdx.x;
    double z[NE];
#pragma unroll
    for (int e = 0; e < NE; e++) z[e] = 0.0;
    const float* xrow = x + (size_t)t * DIM;
#pragma unroll
    for (int i = 0; i < 16; i++) {
        int d = i * 64 + l;
        double xv = (double)xrow[d];
        const float4* wr = (const float4*)(Wr + d * NE);
        float4 w0 = wr[0], w1 = wr[1], w2 = wr[2], w3 = wr[3];
        z[0]  += xv * w0.x; z[1]  += xv * w0.y; z[2]  += xv * w0.z; z[3]  += xv * w0.w;
        z[4]  += xv * w1.x; z[5]  += xv * w1.y; z[6]  += xv * w1.z; z[7]  += xv * w1.w;
        z[8]  += xv * w2.x; z[9]  += xv * w2.y; z[10] += xv * w2.z; z[11] += xv * w2.w;
        z[12] += xv * w3.x; z[13] += xv * w3.y; z[14] += xv * w3.z; z[15] += xv * w3.w;
    }
#pragma unroll
    for (int e = 0; e < NE; e++) {
#pragma unroll
        for (int m = 1; m < 64; m <<= 1) z[e] += __shfl_xor(z[e], m, 64);
    }
    if (l == 0) {
        bool taken[NE];
#pragma unroll
        for (int e = 0; e < NE; e++) taken[e] = false;
        int idx[TOPK]; double sel[TOPK];
        for (int k = 0; k < TOPK; k++) {
            int bi = 0; double bv = -1.0e300;
            for (int e = 0; e < NE; e++)
                if (!taken[e] && z[e] > bv) { bv = z[e]; bi = e; }
            taken[bi] = true; idx[k] = bi; sel[k] = bv;
        }
        double m = sel[0];
        double ex[TOPK]; double s = 0.0;
        for (int k = 0; k < TOPK; k++) { ex[k] = exp(sel[k] - m); s += ex[k]; }
        for (int k = 0; k < TOPK; k++) {
            tokIdx[t * TOPK + k] = idx[k];
            tokW[t * TOPK + k]   = (float)(ex[k] / s);
        }
    }
}

// ------------------------------------------------------------------ binning --
// 16 waves, wave e packs expert e via ballot/rank. ptile = 128-padded tile base.
__global__ __launch_bounds__(1024) void bin_kernel(
    const int* __restrict__ tokIdx, const float* __restrict__ tokW,
    int* __restrict__ cnt, int* __restrict__ ptile,
    int* __restrict__ btok, float* __restrict__ bwt)
{
    int wv = threadIdx.x >> 6;
    int lane = threadIdx.x & 63;
    __shared__ int scnt[NE];

    int c = 0;
    for (int i0 = lane * 4; i0 < NPAIR; i0 += 256) {
        int4 v = *(const int4*)(tokIdx + i0);
        c += (v.x == wv) + (v.y == wv) + (v.z == wv) + (v.w == wv);
    }
#pragma unroll
    for (int m = 1; m < 64; m <<= 1) c += __shfl_xor(c, m, 64);
    if (lane == 0) scnt[wv] = c;
    __syncthreads();
    if (threadIdx.x == 0) {
        int rt = 0;
        for (int e = 0; e < NE; e++) {
            cnt[e] = scnt[e];
            ptile[e] = rt;
            rt += (scnt[e] + 127) >> 7;
        }
    }

    int pos = 0;
    for (int i0b = 0; i0b < NPAIR; i0b += 256) {
        int i0 = i0b + lane * 4;
        int4 v = *(const int4*)(tokIdx + i0);
        int ev[4] = {v.x, v.y, v.z, v.w};
#pragma unroll
        for (int j = 0; j < 4; j++) {
            bool m = (ev[j] == wv);
            unsigned long long bal = __ballot(m);
            if (m) {
                int r = __popcll(bal & ((1ULL << lane) - 1ULL));
                int p = i0 + j;
                btok[wv * CAP + pos + r] = p >> 2;
                bwt [wv * CAP + pos + r] = tokW[p];
            }
            pos += __popcll(bal);
        }
    }
}

// ------------------------------------------------------------------ casts ----
__global__ __launch_bounds__(256) void cast_x_kernel(
    const float* __restrict__ x, unsigned short* __restrict__ xb)
{
    size_t base = ((size_t)blockIdx.x * 256 + threadIdx.x) * 8;
    float4 a = *(const float4*)(x + base);
    float4 b = *(const float4*)(x + base + 4);
    union { unsigned short u[8]; uint4 v; } p;
    p.u[0] = __builtin_bit_cast(unsigned short, (_Float16)a.x);
    p.u[1] = __builtin_bit_cast(unsigned short, (_Float16)a.y);
    p.u[2] = __builtin_bit_cast(unsigned short, (_Float16)a.z);
    p.u[3] = __builtin_bit_cast(unsigned short, (_Float16)a.w);
    p.u[4] = __builtin_bit_cast(unsigned short, (_Float16)b.x);
    p.u[5] = __builtin_bit_cast(unsigned short, (_Float16)b.y);
    p.u[6] = __builtin_bit_cast(unsigned short, (_Float16)b.z);
    p.u[7] = __builtin_bit_cast(unsigned short, (_Float16)b.w);
    *(uint4*)(xb + base) = p.v;
}

// src [E][R][C] f32 -> B^T tiled+swizzled f16 images:
// out[e][cb][kt][RI][32], cb over C/RI row-blocks, kt over R/32; chunk^=(row&3).
__global__ __launch_bounds__(256) void tile_weight_kernel(
    const float* __restrict__ src, unsigned short* __restrict__ dst,
    int R, int C, int RIL)   // RIL = log2(rows per image)
{
    __shared__ float tile[64][65];
    int e = blockIdx.z;
    const float* s = src + (size_t)e * R * C;
    int c0 = blockIdx.x * 64, r0 = blockIdx.y * 64;
    int t = threadIdx.x;
    int tr = t >> 4, tc = (t & 15) * 4;
#pragma unroll
    for (int i = 0; i < 4; i++) {
        int row = i * 16 + tr;
        float4 v = *(const float4*)(s + (size_t)(r0 + row) * C + c0 + tc);
        tile[row][tc + 0] = v.x; tile[row][tc + 1] = v.y;
        tile[row][tc + 2] = v.z; tile[row][tc + 3] = v.w;
    }
    __syncthreads();
    int ktPerE = R >> 5;
    int cbPerE = C >> RIL;
    int imgSz  = (1 << RIL) * 32;
#pragma unroll
    for (int i = 0; i < 4; i++) {
        int nr = i * 16 + tr;
        int orow = c0 + nr;               // output row (f or d)
        int k0 = r0 + tc;                 // 4 consecutive k
        int cb = orow >> RIL;
        int r  = orow & ((1 << RIL) - 1);
        int kt = k0 >> 5;
        int cc = (k0 & 31) >> 3;
        int i0 = k0 & 7;                  // 0 or 4
        int phys = cc ^ (r & 3);
        size_t off = ((size_t)(e * cbPerE + cb) * ktPerE + kt) * imgSz
                   + r * 32 + phys * 8 + i0;
        union { unsigned short u[4]; uint2 v; } p;
#pragma unroll
        for (int j = 0; j < 4; j++)
            p.u[j] = __builtin_bit_cast(unsigned short, (_Float16)tile[tc + j][nr]);
        *(uint2*)(dst + off) = p.v;
    }
}

// --------------------------------------------------------- gate/up + silu ----
// block: 128 slots x 64 f-cols; weights DMA'd via global_load_lds; X gathered
// with one-K-step register prefetch; h written in tiled-image layout.
__global__ __launch_bounds__(256) void ffn_gate_up_kernel(
    const unsigned short* __restrict__ xb,
    const unsigned short* __restrict__ Wg_t,   // [e][fb8][kt32][64][32]
    const unsigned short* __restrict__ Wu_t,
    const int* __restrict__ cnt, const int* __restrict__ ptile,
    const int* __restrict__ btok,
    unsigned short* __restrict__ h_t)          // [tile][kt16][128][32]
{
    int e = blockIdx.z, mt = blockIdx.x, fb = blockIdx.y;
    int count = cnt[e];
    if (mt * 128 >= count) return;

    __shared__ __align__(16) unsigned short sX[128 * 32];
    __shared__ __align__(16) unsigned short sG[64 * 32];
    __shared__ __align__(16) unsigned short sU[64 * 32];
    __shared__ int sTok[128];

    int tid = threadIdx.x, lane = tid & 63, w = tid >> 6;
    if (tid < 128) {
        int pos = mt * 128 + tid;
        sTok[tid] = btok[e * CAP + min(pos, count - 1)];
    }
    __syncthreads();

    // X staging: thread owns chunks tid and tid+256 (of 512 16B-chunks)
    int r1 = tid >> 2, cc1 = tid & 3;
    int r2 = (tid + 256) >> 2, cc2 = tid & 3;
    const unsigned short* xs1 = xb + (size_t)sTok[r1] * DIM + cc1 * 8;
    const unsigned short* xs2 = xb + (size_t)sTok[r2] * DIM + cc2 * 8;
    unsigned short* wx1 = &sX[r1 * 32 + (cc1 ^ (r1 & 3)) * 8];
    unsigned short* wx2 = &sX[r2 * 32 + (cc2 ^ (r2 & 3)) * 8];

    const unsigned short* gsrc = Wg_t + ((size_t)(e * 8 + fb) * 32) * 2048 + w * 512 + lane * 8;
    const unsigned short* usrc = Wu_t + ((size_t)(e * 8 + fb) * 32) * 2048 + w * 512 + lane * 8;

    int row = lane & 15, q = lane >> 4;
    int rw = w & 1, cw = w >> 1;
    int aoff[4], goff[2];
#pragma unroll
    for (int mi = 0; mi < 4; mi++) {
        int ra = rw * 64 + mi * 16 + row;
        aoff[mi] = ra * 32 + (q ^ (ra & 3)) * 8;
    }
#pragma unroll
    for (int ni = 0; ni < 2; ni++) {
        int rg = cw * 32 + ni * 16 + row;
        goff[ni] = rg * 32 + (q ^ (rg & 3)) * 8;
    }

    v4f accG[4][2], accU[4][2];
    v4f zero = {0.f, 0.f, 0.f, 0.f};
#pragma unroll
    for (int mi = 0; mi < 4; mi++)
#pragma unroll
        for (int ni = 0; ni < 2; ni++) { accG[mi][ni] = zero; accU[mi][ni] = zero; }

    uint4 px1 = *(const uint4*)(xs1);
    uint4 px2 = *(const uint4*)(xs2);

    for (int kt = 0; kt < 32; kt++) {
        __syncthreads();                                  // prev-iter reads done
        async_load16(gsrc + (size_t)kt * 2048, &sG[w * 512]);
        async_load16(usrc + (size_t)kt * 2048, &sU[w * 512]);
        *(uint4*)wx1 = px1;
        *(uint4*)wx2 = px2;
        if (kt < 31) {                                    // prefetch next K-step
            px1 = *(const uint4*)(xs1 + (kt + 1) * 32);
            px2 = *(const uint4*)(xs2 + (kt + 1) * 32);
        }
        __syncthreads();                                  // drains vmcnt + lgkm
        v8h a[4], bg[2], bu[2];
#pragma unroll
        for (int mi = 0; mi < 4; mi++) a[mi] = *(const v8h*)&sX[aoff[mi]];
#pragma unroll
        for (int ni = 0; ni < 2; ni++) {
            bg[ni] = *(const v8h*)&sG[goff[ni]];
            bu[ni] = *(const v8h*)&sU[goff[ni]];
        }
#pragma unroll
        for (int mi = 0; mi < 4; mi++)
#pragma unroll
            for (int ni = 0; ni < 2; ni++) {
                accG[mi][ni] = __builtin_amdgcn_mfma_f32_16x16x32_f16(a[mi], bg[ni], accG[mi][ni], 0, 0, 0);
                accU[mi][ni] = __builtin_amdgcn_mfma_f32_16x16x32_f16(a[mi], bu[ni], accU[mi][ni], 0, 0, 0);
            }
    }

    size_t himg = (size_t)(ptile[e] + mt) * 16;
#pragma unroll
    for (int mi = 0; mi < 4; mi++)
#pragma unroll
        for (int ni = 0; ni < 2; ni++) {
            int f = fb * 64 + cw * 32 + ni * 16 + row;    // C/D: col = lane&15
#pragma unroll
            for (int i = 0; i < 4; i++) {
                int rl = rw * 64 + mi * 16 + q * 4 + i;   // C/D: row = quad*4+reg
                int pos = mt * 128 + rl;
                if (pos < count) {
                    float gv = accG[mi][ni][i];
                    float uv = accU[mi][ni][i];
                    float hv = gv * uv / (1.0f + __expf(-gv));
                    size_t off = (himg + (f >> 5)) * 4096 + rl * 32
                               + (((f & 31) >> 3) ^ (rl & 3)) * 8 + (f & 7);
                    h_t[off] = __builtin_bit_cast(unsigned short, (_Float16)hv);
                }
            }
        }
}

// ----------------------------------------------------------- down + combine --
// block: 128 slots x 128 d-cols; H and Wd both DMA'd (tiled images).
__global__ __launch_bounds__(256) void ffn_down_kernel(
    const unsigned short* __restrict__ h_t,
    const unsigned short* __restrict__ Wd_t,   // [e][db8][kt16][128][32]
    const int* __restrict__ cnt, const int* __restrict__ ptile,
    const int* __restrict__ btok, const float* __restrict__ bwt,
    float* __restrict__ out)
{
    int e = blockIdx.z, mt = blockIdx.x, db = blockIdx.y;
    int count = cnt[e];
    if (mt * 128 >= count) return;

    __shared__ __align__(16) unsigned short sH[128 * 32];
    __shared__ __align__(16) unsigned short sW[128 * 32];
    __shared__ int sTok[128];
    __shared__ float sWt[128];

    int tid = threadIdx.x, lane = tid & 63, w = tid >> 6;
    if (tid < 128) {
        int pos = mt * 128 + tid;
        bool in = pos < count;
        sTok[tid] = btok[e * CAP + min(pos, count - 1)];
        sWt[tid]  = in ? bwt[e * CAP + pos] : 0.0f;
    }

    const unsigned short* hsrc = h_t + ((size_t)(ptile[e] + mt) * 16) * 4096 + 2 * w * 512 + lane * 8;
    const unsigned short* wsrc = Wd_t + ((size_t)(e * 8 + db) * 16) * 4096 + 2 * w * 512 + lane * 8;

    int row = lane & 15, q = lane >> 4;
    int rw = w & 1, cw = w >> 1;
    int aoff[4], boff[4];
#pragma unroll
    for (int mi = 0; mi < 4; mi++) {
        int ra = rw * 64 + mi * 16 + row;
        aoff[mi] = ra * 32 + (q ^ (ra & 3)) * 8;
    }
#pragma unroll
    for (int ni = 0; ni < 4; ni++) {
        int rb = cw * 64 + ni * 16 + row;
        boff[ni] = rb * 32 + (q ^ (rb & 3)) * 8;
    }

    v4f acc[4][4];
    v4f zero = {0.f, 0.f, 0.f, 0.f};
#pragma unroll
    for (int mi = 0; mi < 4; mi++)
#pragma unroll
        for (int ni = 0; ni < 4; ni++) acc[mi][ni] = zero;

    for (int kt = 0; kt < 16; kt++) {
        __syncthreads();
        async_load16(hsrc + (size_t)kt * 4096,       &sH[2 * w * 512]);
        async_load16(hsrc + (size_t)kt * 4096 + 512, &sH[(2 * w + 1) * 512]);
        async_load16(wsrc + (size_t)kt * 4096,       &sW[2 * w * 512]);
        async_load16(wsrc + (size_t)kt * 4096 + 512, &sW[(2 * w + 1) * 512]);
        __syncthreads();
        v8h a[4], b[4];
#pragma unroll
        for (int mi = 0; mi < 4; mi++) a[mi] = *(const v8h*)&sH[aoff[mi]];
#pragma unroll
        for (int ni = 0; ni < 4; ni++) b[ni] = *(const v8h*)&sW[boff[ni]];
#pragma unroll
        for (int mi = 0; mi < 4; mi++)
#pragma unroll
            for (int ni = 0; ni < 4; ni++)
                acc[mi][ni] = __builtin_amdgcn_mfma_f32_16x16x32_f16(a[mi], b[ni], acc[mi][ni], 0, 0, 0);
    }

#pragma unroll
    for (int mi = 0; mi < 4; mi++)
#pragma unroll
        for (int ni = 0; ni < 4; ni++) {
            int col = db * 128 + cw * 64 + ni * 16 + row;
#pragma unroll
            for (int i = 0; i < 4; i++) {
                int rl = rw * 64 + mi * 16 + q * 4 + i;
                int pos = mt * 128 + rl;
                if (pos < count) {
                    float v = acc[mi][ni][i] * sWt[rl];
                    atomicAdd(out + (size_t)sTok[rl] * DIM + col, v);
                }
            }
        }
}

// ------------------------------------------------------------------- host ----
extern "C" void kernel_launch(void* const* d_in, const int* in_sizes, int n_in,
                              void* d_out, int out_size, void* d_ws, size_t ws_size,
                              hipStream_t stream)
{
    const float* x  = (const float*)d_in[0];
    const float* Wr = (const float*)d_in[1];
    const float* Wg = (const float*)d_in[2];
    const float* Wu = (const float*)d_in[3];
    const float* Wd = (const float*)d_in[4];
    float* out = (float*)d_out;
    char* ws = (char*)d_ws;

    size_t off = 0;
    int* tokIdx = (int*)(ws + off);   off += (size_t)NPAIR * 4;
    float* tokW = (float*)(ws + off); off += (size_t)NPAIR * 4;
    int* cnt    = (int*)(ws + off);   off += 256;
    int* ptile  = (int*)(ws + off);   off += 256;
    int* btok   = (int*)(ws + off);   off += (size_t)NE * CAP * 4;
    float* bwt  = (float*)(ws + off); off += (size_t)NE * CAP * 4;
    unsigned short* xb   = (unsigned short*)(ws + off); off += (size_t)N_TOK * DIM * 2;
    unsigned short* Wg_t = (unsigned short*)(ws + off); off += (size_t)NE * DIM * NF * 2;
    unsigned short* Wu_t = (unsigned short*)(ws + off); off += (size_t)NE * DIM * NF * 2;
    unsigned short* Wd_t = (unsigned short*)(ws + off); off += (size_t)NE * DIM * NF * 2;
    unsigned short* h_t  = (unsigned short*)(ws + off);
    off += (size_t)MAXTILES * 16 * 4096 * 2;   // ~78.6 MB total

    hipMemsetAsync(out, 0, (size_t)N_TOK * DIM * sizeof(float), stream);

    router_kernel<<<N_TOK, 64, 0, stream>>>(x, Wr, tokIdx, tokW);
    bin_kernel<<<1, 1024, 0, stream>>>(tokIdx, tokW, cnt, ptile, btok, bwt);
    cast_x_kernel<<<(N_TOK * DIM) / (256 * 8), 256, 0, stream>>>(x, xb);
    // Wg/Wu: [E][D=1024][F=512] -> [e][fb=8][kt=32][64][32]
    tile_weight_kernel<<<dim3(NF / 64, DIM / 64, NE), 256, 0, stream>>>(Wg, Wg_t, DIM, NF, 6);
    tile_weight_kernel<<<dim3(NF / 64, DIM / 64, NE), 256, 0, stream>>>(Wu, Wu_t, DIM, NF, 6);
    // Wd: [E][F=512][D=1024] -> [e][db=8][kt=16][128][32]
    tile_weight_kernel<<<dim3(DIM / 64, NF / 64, NE), 256, 0, stream>>>(Wd, Wd_t, NF, DIM, 7);
    ffn_gate_up_kernel<<<dim3(32, 8, NE), 256, 0, stream>>>(xb, Wg_t, Wu_t, cnt, ptile, btok, h_t);
    ffn_down_kernel<<<dim3(32, 8, NE), 256, 0, stream>>>(h_t, Wd_t, cnt, ptile, btok, bwt, out);
}

// Round 4
// 464.694 us; speedup vs baseline: 1.1796x; 1.1796x over previous
//
#include <hip/hip_runtime.h>

#define N_TOK 4096
#define DIM   1024
#define NE    16
#define NF    512
#define TOPK  4
#define CAP   4096
#define NPAIR (N_TOK * TOPK)
#define MAXTILES 144   // sum ceil(cnt/128) <= 128 + 16

typedef _Float16 v8h __attribute__((ext_vector_type(8)));
typedef float    v4f __attribute__((ext_vector_type(4)));

// direct global->LDS DMA, 16B/lane, wave-uniform LDS base
__device__ __forceinline__ void async_load16(const void* g, void* l) {
    __builtin_amdgcn_global_load_lds(
        reinterpret_cast<const __attribute__((address_space(1))) unsigned int*>(
            reinterpret_cast<uintptr_t>(g)),
        reinterpret_cast<__attribute__((address_space(3))) unsigned int*>(
            reinterpret_cast<uintptr_t>(l)),
        16, 0, 0);
}
// raw pipeline controls: never let __syncthreads drain the DMA queue
#define WAITCNT_VM4()  asm volatile("s_waitcnt vmcnt(4)" ::: "memory")
#define WAITCNT_VM0()  asm volatile("s_waitcnt vmcnt(0)" ::: "memory")
#define RAW_BARRIER()  asm volatile("s_barrier" ::: "memory")

// ---------------------------------------------------------------- router ----
__global__ __launch_bounds__(64) void router_kernel(
    const float* __restrict__ x, const float* __restrict__ Wr,
    int* __restrict__ tokIdx, float* __restrict__ tokW)
{
    int t = blockIdx.x;
    int l = threadIdx.x;
    double z[NE];
#pragma unroll
    for (int e = 0; e < NE; e++) z[e] = 0.0;
    const float* xrow = x + (size_t)t * DIM;
#pragma unroll
    for (int i = 0; i < 16; i++) {
        int d = i * 64 + l;
        double xv = (double)xrow[d];
        const float4* wr = (const float4*)(Wr + d * NE);
        float4 w0 = wr[0], w1 = wr[1], w2 = wr[2], w3 = wr[3];
        z[0]  += xv * w0.x; z[1]  += xv * w0.y; z[2]  += xv * w0.z; z[3]  += xv * w0.w;
        z[4]  += xv * w1.x; z[5]  += xv * w1.y; z[6]  += xv * w1.z; z[7]  += xv * w1.w;
        z[8]  += xv * w2.x; z[9]  += xv * w2.y; z[10] += xv * w2.z; z[11] += xv * w2.w;
        z[12] += xv * w3.x; z[13] += xv * w3.y; z[14] += xv * w3.z; z[15] += xv * w3.w;
    }
#pragma unroll
    for (int e = 0; e < NE; e++) {
#pragma unroll
        for (int m = 1; m < 64; m <<= 1) z[e] += __shfl_xor(z[e], m, 64);
    }
    if (l == 0) {
        bool taken[NE];
#pragma unroll
        for (int e = 0; e < NE; e++) taken[e] = false;
        int idx[TOPK]; double sel[TOPK];
        for (int k = 0; k < TOPK; k++) {
            int bi = 0; double bv = -1.0e300;
            for (int e = 0; e < NE; e++)
                if (!taken[e] && z[e] > bv) { bv = z[e]; bi = e; }
            taken[bi] = true; idx[k] = bi; sel[k] = bv;
        }
        double m = sel[0];
        double ex[TOPK]; double s = 0.0;
        for (int k = 0; k < TOPK; k++) { ex[k] = exp(sel[k] - m); s += ex[k]; }
        for (int k = 0; k < TOPK; k++) {
            tokIdx[t * TOPK + k] = idx[k];
            tokW[t * TOPK + k]   = (float)(ex[k] / s);
        }
    }
}

// ------------------------------------------------------------------ binning --
// 16 waves, wave e packs expert e via ballot/rank. Buckets store PAIR index
// (token*4+k) so the down kernel can write non-atomic per-pair partials.
__global__ __launch_bounds__(1024) void bin_kernel(
    const int* __restrict__ tokIdx,
    int* __restrict__ cnt, int* __restrict__ ptile,
    int* __restrict__ bpair)
{
    int wv = threadIdx.x >> 6;
    int lane = threadIdx.x & 63;
    __shared__ int scnt[NE];

    int c = 0;
    for (int i0 = lane * 4; i0 < NPAIR; i0 += 256) {
        int4 v = *(const int4*)(tokIdx + i0);
        c += (v.x == wv) + (v.y == wv) + (v.z == wv) + (v.w == wv);
    }
#pragma unroll
    for (int m = 1; m < 64; m <<= 1) c += __shfl_xor(c, m, 64);
    if (lane == 0) scnt[wv] = c;
    __syncthreads();
    if (threadIdx.x == 0) {
        int rt = 0;
        for (int e = 0; e < NE; e++) {
            cnt[e] = scnt[e];
            ptile[e] = rt;
            rt += (scnt[e] + 127) >> 7;
        }
    }

    int pos = 0;
    for (int i0b = 0; i0b < NPAIR; i0b += 256) {
        int i0 = i0b + lane * 4;
        int4 v = *(const int4*)(tokIdx + i0);
        int ev[4] = {v.x, v.y, v.z, v.w};
#pragma unroll
        for (int j = 0; j < 4; j++) {
            bool m = (ev[j] == wv);
            unsigned long long bal = __ballot(m);
            if (m) {
                int r = __popcll(bal & ((1ULL << lane) - 1ULL));
                bpair[wv * CAP + pos + r] = i0 + j;   // pair index
            }
            pos += __popcll(bal);
        }
    }
}

// ------------------------------------------------------------------ casts ----
__global__ __launch_bounds__(256) void cast_x_kernel(
    const float* __restrict__ x, unsigned short* __restrict__ xb)
{
    size_t base = ((size_t)blockIdx.x * 256 + threadIdx.x) * 8;
    float4 a = *(const float4*)(x + base);
    float4 b = *(const float4*)(x + base + 4);
    union { unsigned short u[8]; uint4 v; } p;
    p.u[0] = __builtin_bit_cast(unsigned short, (_Float16)a.x);
    p.u[1] = __builtin_bit_cast(unsigned short, (_Float16)a.y);
    p.u[2] = __builtin_bit_cast(unsigned short, (_Float16)a.z);
    p.u[3] = __builtin_bit_cast(unsigned short, (_Float16)a.w);
    p.u[4] = __builtin_bit_cast(unsigned short, (_Float16)b.x);
    p.u[5] = __builtin_bit_cast(unsigned short, (_Float16)b.y);
    p.u[6] = __builtin_bit_cast(unsigned short, (_Float16)b.z);
    p.u[7] = __builtin_bit_cast(unsigned short, (_Float16)b.w);
    *(uint4*)(xb + base) = p.v;
}

// src [E][R][C] f32 -> B^T tiled+swizzled f16 images:
// out[e][cb][kt][RI][32]; chunk ^= (row&3) baked into global layout.
__global__ __launch_bounds__(256) void tile_weight_kernel(
    const float* __restrict__ src, unsigned short* __restrict__ dst,
    int R, int C, int RIL)
{
    __shared__ float tile[64][65];
    int e = blockIdx.z;
    const float* s = src + (size_t)e * R * C;
    int c0 = blockIdx.x * 64, r0 = blockIdx.y * 64;
    int t = threadIdx.x;
    int tr = t >> 4, tc = (t & 15) * 4;
#pragma unroll
    for (int i = 0; i < 4; i++) {
        int row = i * 16 + tr;
        float4 v = *(const float4*)(s + (size_t)(r0 + row) * C + c0 + tc);
        tile[row][tc + 0] = v.x; tile[row][tc + 1] = v.y;
        tile[row][tc + 2] = v.z; tile[row][tc + 3] = v.w;
    }
    __syncthreads();
    int ktPerE = R >> 5;
    int cbPerE = C >> RIL;
    int imgSz  = (1 << RIL) * 32;
#pragma unroll
    for (int i = 0; i < 4; i++) {
        int nr = i * 16 + tr;
        int orow = c0 + nr;
        int k0 = r0 + tc;
        int cb = orow >> RIL;
        int r  = orow & ((1 << RIL) - 1);
        int kt = k0 >> 5;
        int cc = (k0 & 31) >> 3;
        int i0 = k0 & 7;
        int phys = cc ^ (r & 3);
        size_t off = ((size_t)(e * cbPerE + cb) * ktPerE + kt) * imgSz
                   + r * 32 + phys * 8 + i0;
        union { unsigned short u[4]; uint2 v; } p;
#pragma unroll
        for (int j = 0; j < 4; j++)
            p.u[j] = __builtin_bit_cast(unsigned short, (_Float16)tile[tc + j][nr]);
        *(uint2*)(dst + off) = p.v;
    }
}

// --------------------------------------------------------- gate/up + silu ----
// 128 slots x 64 f-cols. Everything DMA-staged; double-buffered LDS;
// raw s_barrier + vmcnt(4) pipeline (never drain until last step).
__global__ __launch_bounds__(256) void ffn_gate_up_kernel(
    const unsigned short* __restrict__ xb,
    const unsigned short* __restrict__ Wg_t,   // [e][fb8][kt32][64][32]
    const unsigned short* __restrict__ Wu_t,
    const int* __restrict__ cnt, const int* __restrict__ ptile,
    const int* __restrict__ bpair,
    unsigned short* __restrict__ h_t)          // [tile][kt16][128][32]
{
    int e = blockIdx.z, mt = blockIdx.x, fb = blockIdx.y;
    int count = cnt[e];
    if (mt * 128 >= count) return;

    __shared__ __align__(16) unsigned short sX[2][128 * 32];
    __shared__ __align__(16) unsigned short sG[2][64 * 32];
    __shared__ __align__(16) unsigned short sU[2][64 * 32];
    __shared__ int sTok[128];

    int tid = threadIdx.x, lane = tid & 63, w = tid >> 6;
    if (tid < 128) {
        int pos = mt * 128 + tid;
        sTok[tid] = bpair[e * CAP + min(pos, count - 1)] >> 2;  // token id
    }
    __syncthreads();

    // X DMA addressing: wave w covers rows [w*32, w*32+32), 2 DMAs (16 rows ea)
    int xr0 = w * 32 + (lane >> 2);
    int xr1 = xr0 + 16;
    int cs0 = (lane & 3) ^ (xr0 & 3);          // swizzle baked via source chunk
    int cs1 = (lane & 3) ^ (xr1 & 3);
    const unsigned short* gx0 = xb + (size_t)sTok[xr0] * DIM + cs0 * 8;
    const unsigned short* gx1 = xb + (size_t)sTok[xr1] * DIM + cs1 * 8;

    const unsigned short* gsrc = Wg_t + ((size_t)(e * 8 + fb) * 32) * 2048 + w * 512 + lane * 8;
    const unsigned short* usrc = Wu_t + ((size_t)(e * 8 + fb) * 32) * 2048 + w * 512 + lane * 8;

    int row = lane & 15, q = lane >> 4;
    int rw = w & 1, cw = w >> 1;
    int aoff[4], goff[2];
#pragma unroll
    for (int mi = 0; mi < 4; mi++) {
        int ra = rw * 64 + mi * 16 + row;
        aoff[mi] = ra * 32 + (q ^ (ra & 3)) * 8;
    }
#pragma unroll
    for (int ni = 0; ni < 2; ni++) {
        int rg = cw * 32 + ni * 16 + row;
        goff[ni] = rg * 32 + (q ^ (rg & 3)) * 8;
    }

    v4f accG[4][2], accU[4][2];
    v4f zero = {0.f, 0.f, 0.f, 0.f};
#pragma unroll
    for (int mi = 0; mi < 4; mi++)
#pragma unroll
        for (int ni = 0; ni < 2; ni++) { accG[mi][ni] = zero; accU[mi][ni] = zero; }

    // prologue: kt=0 into buf 0 (4 DMAs per wave)
    async_load16(gx0,  &sX[0][(w * 32) * 32]);
    async_load16(gx1,  &sX[0][(w * 32 + 16) * 32]);
    async_load16(gsrc, &sG[0][w * 512]);
    async_load16(usrc, &sU[0][w * 512]);

#pragma unroll 1
    for (int kt = 0; kt < 31; kt++) {
        int cur = kt & 1, nxt = cur ^ 1;
        // issue kt+1 into the other buffer
        async_load16(gx0 + (kt + 1) * 32, &sX[nxt][(w * 32) * 32]);
        async_load16(gx1 + (kt + 1) * 32, &sX[nxt][(w * 32 + 16) * 32]);
        async_load16(gsrc + (size_t)(kt + 1) * 2048, &sG[nxt][w * 512]);
        async_load16(usrc + (size_t)(kt + 1) * 2048, &sU[nxt][w * 512]);
        WAITCNT_VM4();            // kt's 4 DMAs done (kt+1's still in flight)
        RAW_BARRIER();            // all waves' kt data resident
        v8h a[4], bg[2], bu[2];
#pragma unroll
        for (int mi = 0; mi < 4; mi++) a[mi] = *(const v8h*)&sX[cur][aoff[mi]];
#pragma unroll
        for (int ni = 0; ni < 2; ni++) {
            bg[ni] = *(const v8h*)&sG[cur][goff[ni]];
            bu[ni] = *(const v8h*)&sU[cur][goff[ni]];
        }
#pragma unroll
        for (int mi = 0; mi < 4; mi++)
#pragma unroll
            for (int ni = 0; ni < 2; ni++) {
                accG[mi][ni] = __builtin_amdgcn_mfma_f32_16x16x32_f16(a[mi], bg[ni], accG[mi][ni], 0, 0, 0);
                accU[mi][ni] = __builtin_amdgcn_mfma_f32_16x16x32_f16(a[mi], bu[ni], accU[mi][ni], 0, 0, 0);
            }
        RAW_BARRIER();            // reads of 'cur' done before it's re-targeted
    }
    {   // peeled last step (kt=31, buf 1)
        WAITCNT_VM0();
        RAW_BARRIER();
        v8h a[4], bg[2], bu[2];
#pragma unroll
        for (int mi = 0; mi < 4; mi++) a[mi] = *(const v8h*)&sX[1][aoff[mi]];
#pragma unroll
        for (int ni = 0; ni < 2; ni++) {
            bg[ni] = *(const v8h*)&sG[1][goff[ni]];
            bu[ni] = *(const v8h*)&sU[1][goff[ni]];
        }
#pragma unroll
        for (int mi = 0; mi < 4; mi++)
#pragma unroll
            for (int ni = 0; ni < 2; ni++) {
                accG[mi][ni] = __builtin_amdgcn_mfma_f32_16x16x32_f16(a[mi], bg[ni], accG[mi][ni], 0, 0, 0);
                accU[mi][ni] = __builtin_amdgcn_mfma_f32_16x16x32_f16(a[mi], bu[ni], accU[mi][ni], 0, 0, 0);
            }
    }

    size_t himg = (size_t)(ptile[e] + mt) * 16;
#pragma unroll
    for (int mi = 0; mi < 4; mi++)
#pragma unroll
        for (int ni = 0; ni < 2; ni++) {
            int f = fb * 64 + cw * 32 + ni * 16 + row;    // C/D: col = lane&15
#pragma unroll
            for (int i = 0; i < 4; i++) {
                int rl = rw * 64 + mi * 16 + q * 4 + i;   // C/D: row = quad*4+reg
                int pos = mt * 128 + rl;
                if (pos < count) {
                    float gv = accG[mi][ni][i];
                    float uv = accU[mi][ni][i];
                    float hv = gv * uv / (1.0f + __expf(-gv));
                    size_t off = (himg + (f >> 5)) * 4096 + rl * 32
                               + (((f & 31) >> 3) ^ (rl & 3)) * 8 + (f & 7);
                    h_t[off] = __builtin_bit_cast(unsigned short, (_Float16)hv);
                }
            }
        }
}

// ----------------------------------------------------------- down (no atomics)
// 128 slots x 128 d-cols; H and Wd DMA'd; partials written per-pair, f16.
__global__ __launch_bounds__(256) void ffn_down_kernel(
    const unsigned short* __restrict__ h_t,
    const unsigned short* __restrict__ Wd_t,   // [e][db8][kt16][128][32]
    const int* __restrict__ cnt, const int* __restrict__ ptile,
    const int* __restrict__ bpair,
    unsigned short* __restrict__ part)         // [NPAIR][DIM] f16
{
    int e = blockIdx.z, mt = blockIdx.x, db = blockIdx.y;
    int count = cnt[e];
    if (mt * 128 >= count) return;

    __shared__ __align__(16) unsigned short sH[2][128 * 32];
    __shared__ __align__(16) unsigned short sW[2][128 * 32];
    __shared__ int sPair[128];

    int tid = threadIdx.x, lane = tid & 63, w = tid >> 6;
    if (tid < 128) {
        int pos = mt * 128 + tid;
        sPair[tid] = bpair[e * CAP + min(pos, count - 1)];
    }
    __syncthreads();

    const unsigned short* hsrc = h_t + ((size_t)(ptile[e] + mt) * 16) * 4096 + 2 * w * 512 + lane * 8;
    const unsigned short* wsrc = Wd_t + ((size_t)(e * 8 + db) * 16) * 4096 + 2 * w * 512 + lane * 8;

    int row = lane & 15, q = lane >> 4;
    int rw = w & 1, cw = w >> 1;
    int aoff[4], boff[4];
#pragma unroll
    for (int mi = 0; mi < 4; mi++) {
        int ra = rw * 64 + mi * 16 + row;
        aoff[mi] = ra * 32 + (q ^ (ra & 3)) * 8;
    }
#pragma unroll
    for (int ni = 0; ni < 4; ni++) {
        int rb = cw * 64 + ni * 16 + row;
        boff[ni] = rb * 32 + (q ^ (rb & 3)) * 8;
    }

    v4f acc[4][4];
    v4f zero = {0.f, 0.f, 0.f, 0.f};
#pragma unroll
    for (int mi = 0; mi < 4; mi++)
#pragma unroll
        for (int ni = 0; ni < 4; ni++) acc[mi][ni] = zero;

    // prologue kt=0
    async_load16(hsrc,       &sH[0][2 * w * 512]);
    async_load16(hsrc + 512, &sH[0][(2 * w + 1) * 512]);
    async_load16(wsrc,       &sW[0][2 * w * 512]);
    async_load16(wsrc + 512, &sW[0][(2 * w + 1) * 512]);

#pragma unroll 1
    for (int kt = 0; kt < 15; kt++) {
        int cur = kt & 1, nxt = cur ^ 1;
        async_load16(hsrc + (size_t)(kt + 1) * 4096,       &sH[nxt][2 * w * 512]);
        async_load16(hsrc + (size_t)(kt + 1) * 4096 + 512, &sH[nxt][(2 * w + 1) * 512]);
        async_load16(wsrc + (size_t)(kt + 1) * 4096,       &sW[nxt][2 * w * 512]);
        async_load16(wsrc + (size_t)(kt + 1) * 4096 + 512, &sW[nxt][(2 * w + 1) * 512]);
        WAITCNT_VM4();
        RAW_BARRIER();
        v8h a[4], b[4];
#pragma unroll
        for (int mi = 0; mi < 4; mi++) a[mi] = *(const v8h*)&sH[cur][aoff[mi]];
#pragma unroll
        for (int ni = 0; ni < 4; ni++) b[ni] = *(const v8h*)&sW[cur][boff[ni]];
#pragma unroll
        for (int mi = 0; mi < 4; mi++)
#pragma unroll
            for (int ni = 0; ni < 4; ni++)
                acc[mi][ni] = __builtin_amdgcn_mfma_f32_16x16x32_f16(a[mi], b[ni], acc[mi][ni], 0, 0, 0);
        RAW_BARRIER();
    }
    {   // peeled kt=15 (buf 1)
        WAITCNT_VM0();
        RAW_BARRIER();
        v8h a[4], b[4];
#pragma unroll
        for (int mi = 0; mi < 4; mi++) a[mi] = *(const v8h*)&sH[1][aoff[mi]];
#pragma unroll
        for (int ni = 0; ni < 4; ni++) b[ni] = *(const v8h*)&sW[1][boff[ni]];
#pragma unroll
        for (int mi = 0; mi < 4; mi++)
#pragma unroll
            for (int ni = 0; ni < 4; ni++)
                acc[mi][ni] = __builtin_amdgcn_mfma_f32_16x16x32_f16(a[mi], b[ni], acc[mi][ni], 0, 0, 0);
    }

#pragma unroll
    for (int mi = 0; mi < 4; mi++)
#pragma unroll
        for (int ni = 0; ni < 4; ni++) {
            int col = db * 128 + cw * 64 + ni * 16 + row;
#pragma unroll
            for (int i = 0; i < 4; i++) {
                int rl = rw * 64 + mi * 16 + q * 4 + i;
                int pos = mt * 128 + rl;
                if (pos < count) {
                    int p = sPair[rl];
                    part[(size_t)p * DIM + col] =
                        __builtin_bit_cast(unsigned short, (_Float16)acc[mi][ni][i]);
                }
            }
        }
}

// ---------------------------------------------------------------- combine ----
// out[t][d] = sum_k tokW[t*4+k] * part[t*4+k][d]
__global__ __launch_bounds__(256) void combine_kernel(
    const unsigned short* __restrict__ part, const float* __restrict__ tokW,
    float* __restrict__ out)
{
    int gid = blockIdx.x * 256 + threadIdx.x;
    int t = gid >> 8;
    int c = (gid & 255) * 4;
    float4 r = {0.f, 0.f, 0.f, 0.f};
#pragma unroll
    for (int k = 0; k < TOPK; k++) {
        float wk = tokW[t * TOPK + k];
        union { uint2 u; _Float16 h[4]; } cv;
        cv.u = *(const uint2*)(part + ((size_t)(t * TOPK + k)) * DIM + c);
        r.x += wk * (float)cv.h[0];
        r.y += wk * (float)cv.h[1];
        r.z += wk * (float)cv.h[2];
        r.w += wk * (float)cv.h[3];
    }
    *(float4*)(out + (size_t)t * DIM + c) = r;
}

// ------------------------------------------------------------------- host ----
extern "C" void kernel_launch(void* const* d_in, const int* in_sizes, int n_in,
                              void* d_out, int out_size, void* d_ws, size_t ws_size,
                              hipStream_t stream)
{
    const float* x  = (const float*)d_in[0];
    const float* Wr = (const float*)d_in[1];
    const float* Wg = (const float*)d_in[2];
    const float* Wu = (const float*)d_in[3];
    const float* Wd = (const float*)d_in[4];
    float* out = (float*)d_out;
    char* ws = (char*)d_ws;

    size_t off = 0;
    int* tokIdx = (int*)(ws + off);   off += (size_t)NPAIR * 4;
    float* tokW = (float*)(ws + off); off += (size_t)NPAIR * 4;
    int* cnt    = (int*)(ws + off);   off += 256;
    int* ptile  = (int*)(ws + off);   off += 256;
    int* bpair  = (int*)(ws + off);   off += (size_t)NE * CAP * 4;
    unsigned short* xb   = (unsigned short*)(ws + off); off += (size_t)N_TOK * DIM * 2;
    unsigned short* Wg_t = (unsigned short*)(ws + off); off += (size_t)NE * DIM * NF * 2;
    unsigned short* Wu_t = (unsigned short*)(ws + off); off += (size_t)NE * DIM * NF * 2;
    unsigned short* Wd_t = (unsigned short*)(ws + off); off += (size_t)NE * DIM * NF * 2;
    unsigned short* h_t  = (unsigned short*)(ws + off); off += (size_t)MAXTILES * 16 * 4096 * 2;
    unsigned short* part = (unsigned short*)(ws + off); off += (size_t)NPAIR * DIM * 2;
    // total ~107 MB

    router_kernel<<<N_TOK, 64, 0, stream>>>(x, Wr, tokIdx, tokW);
    bin_kernel<<<1, 1024, 0, stream>>>(tokIdx, cnt, ptile, bpair);
    cast_x_kernel<<<(N_TOK * DIM) / (256 * 8), 256, 0, stream>>>(x, xb);
    tile_weight_kernel<<<dim3(NF / 64, DIM / 64, NE), 256, 0, stream>>>(Wg, Wg_t, DIM, NF, 6);
    tile_weight_kernel<<<dim3(NF / 64, DIM / 64, NE), 256, 0, stream>>>(Wu, Wu_t, DIM, NF, 6);
    tile_weight_kernel<<<dim3(DIM / 64, NF / 64, NE), 256, 0, stream>>>(Wd, Wd_t, NF, DIM, 7);
    ffn_gate_up_kernel<<<dim3(32, 8, NE), 256, 0, stream>>>(xb, Wg_t, Wu_t, cnt, ptile, bpair, h_t);
    ffn_down_kernel<<<dim3(32, 8, NE), 256, 0, stream>>>(h_t, Wd_t, cnt, ptile, bpair, part);
    combine_kernel<<<(N_TOK * DIM) / (256 * 4), 256, 0, stream>>>(part, tokW, out);
}

// Round 5
// 325.213 us; speedup vs baseline: 1.6855x; 1.4289x over previous
//
#include <hip/hip_runtime.h>

#define N_TOK 4096
#define DIM   1024
#define NE    16
#define NF    512
#define TOPK  4
#define CAP   4096
#define NPAIR (N_TOK * TOPK)
#define MAXTILES 144   // sum ceil(cnt/128) <= 128 + 16

typedef _Float16 v8h __attribute__((ext_vector_type(8)));
typedef float    v4f __attribute__((ext_vector_type(4)));

// ---------------------------------------------------------------- router ----
__global__ __launch_bounds__(64) void router_kernel(
    const float* __restrict__ x, const float* __restrict__ Wr,
    int* __restrict__ tokIdx, float* __restrict__ tokW)
{
    int t = blockIdx.x;
    int l = threadIdx.x;
    double z[NE];
#pragma unroll
    for (int e = 0; e < NE; e++) z[e] = 0.0;
    const float* xrow = x + (size_t)t * DIM;
#pragma unroll
    for (int i = 0; i < 16; i++) {
        int d = i * 64 + l;
        double xv = (double)xrow[d];
        const float4* wr = (const float4*)(Wr + d * NE);
        float4 w0 = wr[0], w1 = wr[1], w2 = wr[2], w3 = wr[3];
        z[0]  += xv * w0.x; z[1]  += xv * w0.y; z[2]  += xv * w0.z; z[3]  += xv * w0.w;
        z[4]  += xv * w1.x; z[5]  += xv * w1.y; z[6]  += xv * w1.z; z[7]  += xv * w1.w;
        z[8]  += xv * w2.x; z[9]  += xv * w2.y; z[10] += xv * w2.z; z[11] += xv * w2.w;
        z[12] += xv * w3.x; z[13] += xv * w3.y; z[14] += xv * w3.z; z[15] += xv * w3.w;
    }
#pragma unroll
    for (int e = 0; e < NE; e++) {
#pragma unroll
        for (int m = 1; m < 64; m <<= 1) z[e] += __shfl_xor(z[e], m, 64);
    }
    if (l == 0) {
        bool taken[NE];
#pragma unroll
        for (int e = 0; e < NE; e++) taken[e] = false;
        int idx[TOPK]; double sel[TOPK];
        for (int k = 0; k < TOPK; k++) {
            int bi = 0; double bv = -1.0e300;
            for (int e = 0; e < NE; e++)
                if (!taken[e] && z[e] > bv) { bv = z[e]; bi = e; }
            taken[bi] = true; idx[k] = bi; sel[k] = bv;
        }
        double m = sel[0];
        double ex[TOPK]; double s = 0.0;
        for (int k = 0; k < TOPK; k++) { ex[k] = exp(sel[k] - m); s += ex[k]; }
        for (int k = 0; k < TOPK; k++) {
            tokIdx[t * TOPK + k] = idx[k];
            tokW[t * TOPK + k]   = (float)(ex[k] / s);
        }
    }
}

// ------------------------------------------------------------------ binning --
// 16 waves, wave e packs expert e via ballot/rank; emits dense tile work-list.
__global__ __launch_bounds__(1024) void bin_kernel(
    const int* __restrict__ tokIdx,
    int* __restrict__ cnt, int* __restrict__ ptile,
    int* __restrict__ tileE, int* __restrict__ tileMt,
    int* __restrict__ bpair)
{
    int wv = threadIdx.x >> 6;
    int lane = threadIdx.x & 63;
    __shared__ int scnt[NE];

    int c = 0;
    for (int i0 = lane * 4; i0 < NPAIR; i0 += 256) {
        int4 v = *(const int4*)(tokIdx + i0);
        c += (v.x == wv) + (v.y == wv) + (v.z == wv) + (v.w == wv);
    }
#pragma unroll
    for (int m = 1; m < 64; m <<= 1) c += __shfl_xor(c, m, 64);
    if (lane == 0) scnt[wv] = c;
    __syncthreads();
    if (threadIdx.x == 0) {
        int rt = 0;
        for (int e = 0; e < NE; e++) {
            cnt[e] = scnt[e];
            ptile[e] = rt;
            int nt = (scnt[e] + 127) >> 7;
            for (int t = 0; t < nt; t++) { tileE[rt + t] = e; tileMt[rt + t] = t; }
            rt += nt;
        }
        for (; rt < MAXTILES; rt++) tileE[rt] = -1;
    }

    int pos = 0;
    for (int i0b = 0; i0b < NPAIR; i0b += 256) {
        int i0 = i0b + lane * 4;
        int4 v = *(const int4*)(tokIdx + i0);
        int ev[4] = {v.x, v.y, v.z, v.w};
#pragma unroll
        for (int j = 0; j < 4; j++) {
            bool m = (ev[j] == wv);
            unsigned long long bal = __ballot(m);
            if (m) {
                int r = __popcll(bal & ((1ULL << lane) - 1ULL));
                bpair[wv * CAP + pos + r] = i0 + j;   // pair index
            }
            pos += __popcll(bal);
        }
    }
}

// ------------------------------------------------------------------ casts ----
__global__ __launch_bounds__(256) void cast_x_kernel(
    const float* __restrict__ x, unsigned short* __restrict__ xb)
{
    size_t base = ((size_t)blockIdx.x * 256 + threadIdx.x) * 8;
    float4 a = *(const float4*)(x + base);
    float4 b = *(const float4*)(x + base + 4);
    union { unsigned short u[8]; uint4 v; } p;
    p.u[0] = __builtin_bit_cast(unsigned short, (_Float16)a.x);
    p.u[1] = __builtin_bit_cast(unsigned short, (_Float16)a.y);
    p.u[2] = __builtin_bit_cast(unsigned short, (_Float16)a.z);
    p.u[3] = __builtin_bit_cast(unsigned short, (_Float16)a.w);
    p.u[4] = __builtin_bit_cast(unsigned short, (_Float16)b.x);
    p.u[5] = __builtin_bit_cast(unsigned short, (_Float16)b.y);
    p.u[6] = __builtin_bit_cast(unsigned short, (_Float16)b.z);
    p.u[7] = __builtin_bit_cast(unsigned short, (_Float16)b.w);
    *(uint4*)(xb + base) = p.v;
}

// src [E][R][C] f32 -> plain B^T tiled f16 image: out[e][cb][kt][RI][32]
__global__ __launch_bounds__(256) void tile_weight_kernel(
    const float* __restrict__ src, unsigned short* __restrict__ dst,
    int R, int C, int RIL)
{
    __shared__ float tile[64][65];
    int e = blockIdx.z;
    const float* s = src + (size_t)e * R * C;
    int c0 = blockIdx.x * 64, r0 = blockIdx.y * 64;
    int t = threadIdx.x;
    int tr = t >> 4, tc = (t & 15) * 4;
#pragma unroll
    for (int i = 0; i < 4; i++) {
        int row = i * 16 + tr;
        float4 v = *(const float4*)(s + (size_t)(r0 + row) * C + c0 + tc);
        tile[row][tc + 0] = v.x; tile[row][tc + 1] = v.y;
        tile[row][tc + 2] = v.z; tile[row][tc + 3] = v.w;
    }
    __syncthreads();
    int ktPerE = R >> 5;
    int cbPerE = C >> RIL;
    int imgSz  = (1 << RIL) * 32;
#pragma unroll
    for (int i = 0; i < 4; i++) {
        int nr = i * 16 + tr;
        int orow = c0 + nr;
        int k0 = r0 + tc;
        int cb = orow >> RIL;
        int r  = orow & ((1 << RIL) - 1);
        int kt = k0 >> 5;
        size_t off = ((size_t)(e * cbPerE + cb) * ktPerE + kt) * imgSz
                   + r * 32 + (k0 & 31);
        union { unsigned short u[4]; uint2 v; } p;
#pragma unroll
        for (int j = 0; j < 4; j++)
            p.u[j] = __builtin_bit_cast(unsigned short, (_Float16)tile[tc + j][nr]);
        *(uint2*)(dst + off) = p.v;
    }
}

// LDS chunk swizzle: 2-way-max on both ds_write_b128 and frag ds_read_b128
__device__ __forceinline__ int ldsw(int row, int chunk) {
    return row * 32 + (chunk ^ ((row >> 1) & 3)) * 8;
}

// --------------------------------------------------------- gate/up + silu ----
// 128 slots x 64 f-cols; register-staged (loads hoistable across barriers),
// dense work-list grid, XCD-affinity: same (e,fb) -> same id%8.
__global__ __launch_bounds__(256) void ffn_gate_up_kernel(
    const unsigned short* __restrict__ xb,
    const unsigned short* __restrict__ Wg_t,   // [e][fb8][kt32][64][32] plain
    const unsigned short* __restrict__ Wu_t,
    const int* __restrict__ cnt, const int* __restrict__ ptile,
    const int* __restrict__ tileE, const int* __restrict__ tileMt,
    const int* __restrict__ bpair,
    unsigned short* __restrict__ h_t)          // [tile][kt16][128][32] plain
{
    int fb = blockIdx.x, ti = blockIdx.y;
    int e = tileE[ti];
    if (e < 0) return;
    int mt = tileMt[ti];
    int count = cnt[e];

    __shared__ __align__(16) unsigned short sX[128 * 32];
    __shared__ __align__(16) unsigned short sG[64 * 32];
    __shared__ __align__(16) unsigned short sU[64 * 32];
    __shared__ int sTok[128];

    int tid = threadIdx.x, lane = tid & 63, w = tid >> 6;
    if (tid < 128) {
        int pos = mt * 128 + tid;
        sTok[tid] = bpair[e * CAP + min(pos, count - 1)] >> 2;  // token id
    }
    __syncthreads();

    // staging addressing (thread-linear, 4 x uint4 per thread per K-step)
    int xr0 = tid >> 2, xc = tid & 3;          // X rows 0..63 / 64..127
    int xr1 = xr0 + 64;
    const unsigned short* gx0 = xb + (size_t)sTok[xr0] * DIM + xc * 8;
    const unsigned short* gx1 = xb + (size_t)sTok[xr1] * DIM + xc * 8;
    const unsigned short* gsrc = Wg_t + ((size_t)(e * 8 + fb) * 32) * 2048 + tid * 8;
    const unsigned short* usrc = Wu_t + ((size_t)(e * 8 + fb) * 32) * 2048 + tid * 8;

    unsigned short* wx0 = &sX[ldsw(xr0, xc)];
    unsigned short* wx1 = &sX[ldsw(xr1, xc)];
    unsigned short* wg  = &sG[ldsw(xr0, xc)];
    unsigned short* wu  = &sU[ldsw(xr0, xc)];

    int row = lane & 15, q = lane >> 4;
    int rw = w & 1, cw = w >> 1;
    int aoff[4], goff[2];
#pragma unroll
    for (int mi = 0; mi < 4; mi++) aoff[mi] = ldsw(rw * 64 + mi * 16 + row, q);
#pragma unroll
    for (int ni = 0; ni < 2; ni++) goff[ni] = ldsw(cw * 32 + ni * 16 + row, q);

    v4f accG[4][2], accU[4][2];
    v4f zero = {0.f, 0.f, 0.f, 0.f};
#pragma unroll
    for (int mi = 0; mi < 4; mi++)
#pragma unroll
        for (int ni = 0; ni < 2; ni++) { accG[mi][ni] = zero; accU[mi][ni] = zero; }

    // preload kt=0 into registers
    uint4 rx0 = *(const uint4*)(gx0);
    uint4 rx1 = *(const uint4*)(gx1);
    uint4 rg  = *(const uint4*)(gsrc);
    uint4 ru  = *(const uint4*)(usrc);

#pragma unroll 1
    for (int kt = 0; kt < 32; kt++) {
        __syncthreads();                      // prev step's LDS reads done
        *(uint4*)wx0 = rx0;
        *(uint4*)wx1 = rx1;
        *(uint4*)wg  = rg;
        *(uint4*)wu  = ru;
        if (kt < 31) {                        // next step's loads fly over MFMA
            rx0 = *(const uint4*)(gx0 + (kt + 1) * 32);
            rx1 = *(const uint4*)(gx1 + (kt + 1) * 32);
            rg  = *(const uint4*)(gsrc + (size_t)(kt + 1) * 2048);
            ru  = *(const uint4*)(usrc + (size_t)(kt + 1) * 2048);
        }
        __syncthreads();
        v8h a[4], bg[2], bu[2];
#pragma unroll
        for (int mi = 0; mi < 4; mi++) a[mi] = *(const v8h*)&sX[aoff[mi]];
#pragma unroll
        for (int ni = 0; ni < 2; ni++) {
            bg[ni] = *(const v8h*)&sG[goff[ni]];
            bu[ni] = *(const v8h*)&sU[goff[ni]];
        }
#pragma unroll
        for (int mi = 0; mi < 4; mi++)
#pragma unroll
            for (int ni = 0; ni < 2; ni++) {
                accG[mi][ni] = __builtin_amdgcn_mfma_f32_16x16x32_f16(a[mi], bg[ni], accG[mi][ni], 0, 0, 0);
                accU[mi][ni] = __builtin_amdgcn_mfma_f32_16x16x32_f16(a[mi], bu[ni], accU[mi][ni], 0, 0, 0);
            }
    }

    size_t himg = (size_t)(ptile[e] + mt) * 16;
#pragma unroll
    for (int mi = 0; mi < 4; mi++)
#pragma unroll
        for (int ni = 0; ni < 2; ni++) {
            int f = fb * 64 + cw * 32 + ni * 16 + row;    // C/D: col = lane&15
#pragma unroll
            for (int i = 0; i < 4; i++) {
                int rl = rw * 64 + mi * 16 + q * 4 + i;   // C/D: row = quad*4+reg
                int pos = mt * 128 + rl;
                if (pos < count) {
                    float gv = accG[mi][ni][i];
                    float uv = accU[mi][ni][i];
                    float hv = gv * uv / (1.0f + __expf(-gv));
                    size_t off = (himg + (f >> 5)) * 4096 + rl * 32 + (f & 31);
                    h_t[off] = __builtin_bit_cast(unsigned short, (_Float16)hv);
                }
            }
        }
}

// ----------------------------------------------------------- down (no atomics)
// 128 slots x 128 d-cols; register-staged; grid(MAXTILES,8): same-ti -> same XCD.
__global__ __launch_bounds__(256) void ffn_down_kernel(
    const unsigned short* __restrict__ h_t,
    const unsigned short* __restrict__ Wd_t,   // [e][db8][kt16][128][32] plain
    const int* __restrict__ cnt, const int* __restrict__ ptile,
    const int* __restrict__ tileE, const int* __restrict__ tileMt,
    const int* __restrict__ bpair,
    unsigned short* __restrict__ part)         // [NPAIR][DIM] f16
{
    int ti = blockIdx.x, db = blockIdx.y;
    int e = tileE[ti];
    if (e < 0) return;
    int mt = tileMt[ti];
    int count = cnt[e];

    __shared__ __align__(16) unsigned short sH[128 * 32];
    __shared__ __align__(16) unsigned short sW[128 * 32];
    __shared__ int sPair[128];

    int tid = threadIdx.x, lane = tid & 63, w = tid >> 6;
    if (tid < 128) {
        int pos = mt * 128 + tid;
        sPair[tid] = bpair[e * CAP + min(pos, count - 1)];
    }
    __syncthreads();

    int r0 = tid >> 2, c = tid & 3;
    int r1 = r0 + 64;
    const unsigned short* hsrc = h_t + ((size_t)(ptile[e] + mt) * 16) * 4096 + tid * 8;
    const unsigned short* wsrc = Wd_t + ((size_t)(e * 8 + db) * 16) * 4096 + tid * 8;

    unsigned short* wh0 = &sH[ldsw(r0, c)];
    unsigned short* wh1 = &sH[ldsw(r1, c)];
    unsigned short* ww0 = &sW[ldsw(r0, c)];
    unsigned short* ww1 = &sW[ldsw(r1, c)];

    int row = lane & 15, q = lane >> 4;
    int rw = w & 1, cw = w >> 1;
    int aoff[4], boff[4];
#pragma unroll
    for (int mi = 0; mi < 4; mi++) aoff[mi] = ldsw(rw * 64 + mi * 16 + row, q);
#pragma unroll
    for (int ni = 0; ni < 4; ni++) boff[ni] = ldsw(cw * 64 + ni * 16 + row, q);

    v4f acc[4][4];
    v4f zero = {0.f, 0.f, 0.f, 0.f};
#pragma unroll
    for (int mi = 0; mi < 4; mi++)
#pragma unroll
        for (int ni = 0; ni < 4; ni++) acc[mi][ni] = zero;

    uint4 rh0 = *(const uint4*)(hsrc);
    uint4 rh1 = *(const uint4*)(hsrc + 2048);
    uint4 rw0 = *(const uint4*)(wsrc);
    uint4 rw1 = *(const uint4*)(wsrc + 2048);

#pragma unroll 1
    for (int kt = 0; kt < 16; kt++) {
        __syncthreads();
        *(uint4*)wh0 = rh0;
        *(uint4*)wh1 = rh1;
        *(uint4*)ww0 = rw0;
        *(uint4*)ww1 = rw1;
        if (kt < 15) {
            rh0 = *(const uint4*)(hsrc + (size_t)(kt + 1) * 4096);
            rh1 = *(const uint4*)(hsrc + (size_t)(kt + 1) * 4096 + 2048);
            rw0 = *(const uint4*)(wsrc + (size_t)(kt + 1) * 4096);
            rw1 = *(const uint4*)(wsrc + (size_t)(kt + 1) * 4096 + 2048);
        }
        __syncthreads();
        v8h a[4], b[4];
#pragma unroll
        for (int mi = 0; mi < 4; mi++) a[mi] = *(const v8h*)&sH[aoff[mi]];
#pragma unroll
        for (int ni = 0; ni < 4; ni++) b[ni] = *(const v8h*)&sW[boff[ni]];
#pragma unroll
        for (int mi = 0; mi < 4; mi++)
#pragma unroll
            for (int ni = 0; ni < 4; ni++)
                acc[mi][ni] = __builtin_amdgcn_mfma_f32_16x16x32_f16(a[mi], b[ni], acc[mi][ni], 0, 0, 0);
    }

#pragma unroll
    for (int mi = 0; mi < 4; mi++)
#pragma unroll
        for (int ni = 0; ni < 4; ni++) {
            int col = db * 128 + cw * 64 + ni * 16 + row;
#pragma unroll
            for (int i = 0; i < 4; i++) {
                int rl = rw * 64 + mi * 16 + q * 4 + i;
                int pos = mt * 128 + rl;
                if (pos < count) {
                    int p = sPair[rl];
                    part[(size_t)p * DIM + col] =
                        __builtin_bit_cast(unsigned short, (_Float16)acc[mi][ni][i]);
                }
            }
        }
}

// ---------------------------------------------------------------- combine ----
__global__ __launch_bounds__(256) void combine_kernel(
    const unsigned short* __restrict__ part, const float* __restrict__ tokW,
    float* __restrict__ out)
{
    int gid = blockIdx.x * 256 + threadIdx.x;
    int t = gid >> 8;
    int c = (gid & 255) * 4;
    float4 r = {0.f, 0.f, 0.f, 0.f};
#pragma unroll
    for (int k = 0; k < TOPK; k++) {
        float wk = tokW[t * TOPK + k];
        union { uint2 u; _Float16 h[4]; } cv;
        cv.u = *(const uint2*)(part + ((size_t)(t * TOPK + k)) * DIM + c);
        r.x += wk * (float)cv.h[0];
        r.y += wk * (float)cv.h[1];
        r.z += wk * (float)cv.h[2];
        r.w += wk * (float)cv.h[3];
    }
    *(float4*)(out + (size_t)t * DIM + c) = r;
}

// ------------------------------------------------------------------- host ----
extern "C" void kernel_launch(void* const* d_in, const int* in_sizes, int n_in,
                              void* d_out, int out_size, void* d_ws, size_t ws_size,
                              hipStream_t stream)
{
    const float* x  = (const float*)d_in[0];
    const float* Wr = (const float*)d_in[1];
    const float* Wg = (const float*)d_in[2];
    const float* Wu = (const float*)d_in[3];
    const float* Wd = (const float*)d_in[4];
    float* out = (float*)d_out;
    char* ws = (char*)d_ws;

    size_t off = 0;
    int* tokIdx = (int*)(ws + off);   off += (size_t)NPAIR * 4;
    float* tokW = (float*)(ws + off); off += (size_t)NPAIR * 4;
    int* cnt    = (int*)(ws + off);   off += 256;
    int* ptile  = (int*)(ws + off);   off += 256;
    int* tileE  = (int*)(ws + off);   off += MAXTILES * 4;
    int* tileMt = (int*)(ws + off);   off += MAXTILES * 4;
    int* bpair  = (int*)(ws + off);   off += (size_t)NE * CAP * 4;
    unsigned short* xb   = (unsigned short*)(ws + off); off += (size_t)N_TOK * DIM * 2;
    unsigned short* Wg_t = (unsigned short*)(ws + off); off += (size_t)NE * DIM * NF * 2;
    unsigned short* Wu_t = (unsigned short*)(ws + off); off += (size_t)NE * DIM * NF * 2;
    unsigned short* Wd_t = (unsigned short*)(ws + off); off += (size_t)NE * DIM * NF * 2;
    unsigned short* h_t  = (unsigned short*)(ws + off); off += (size_t)MAXTILES * 16 * 4096 * 2;
    unsigned short* part = (unsigned short*)(ws + off); off += (size_t)NPAIR * DIM * 2;

    router_kernel<<<N_TOK, 64, 0, stream>>>(x, Wr, tokIdx, tokW);
    bin_kernel<<<1, 1024, 0, stream>>>(tokIdx, cnt, ptile, tileE, tileMt, bpair);
    cast_x_kernel<<<(N_TOK * DIM) / (256 * 8), 256, 0, stream>>>(x, xb);
    tile_weight_kernel<<<dim3(NF / 64, DIM / 64, NE), 256, 0, stream>>>(Wg, Wg_t, DIM, NF, 6);
    tile_weight_kernel<<<dim3(NF / 64, DIM / 64, NE), 256, 0, stream>>>(Wu, Wu_t, DIM, NF, 6);
    tile_weight_kernel<<<dim3(DIM / 64, NF / 64, NE), 256, 0, stream>>>(Wd, Wd_t, NF, DIM, 7);
    ffn_gate_up_kernel<<<dim3(8, MAXTILES), 256, 0, stream>>>(
        xb, Wg_t, Wu_t, cnt, ptile, tileE, tileMt, bpair, h_t);
    ffn_down_kernel<<<dim3(MAXTILES, 8), 256, 0, stream>>>(
        h_t, Wd_t, cnt, ptile, tileE, tileMt, bpair, part);
    combine_kernel<<<(N_TOK * DIM) / (256 * 4), 256, 0, stream>>>(part, tokW, out);
}